// Round 12
// baseline (229.656 us; speedup 1.0000x reference)
//
#include <hip/hip_runtime.h>
#include <math.h>

#define Bb 8
#define Nn 512
#define Mm 64
#define Dd 128
#define Hh 64
#define NEG_BIG (-1.0e30f)

// per-wave edge buffer: 8 segments of 1KB, each padded +16B -> 260 floats
#define SEGF 260
#define BUFF (8 * SEGF)      // 2080 floats per buffer

typedef __bf16 bf16x8 __attribute__((ext_vector_type(8)));
typedef float  f32x4  __attribute__((ext_vector_type(4)));

// ws byte offsets (16B-aligned)
#define WS_WEB   0u          // 16384 B  bf16 We B-frags, frag-linear [16 frag][64 lane][8]
#define WS_W2B   16384u      // 8192 B   bf16 W2 B-frags, frag-linear [8 frag][64 lane][8]
#define WS_CWSF  24576u      // 131072 B fp32 CwsF[b][w][t][lane][r] (b1 folded, frag-swizzled)
#define WS_AOP   155648u     // 1048576 B fp32 Aop[b*N+n][h]
#define WS_SCORE 1204224u    // 1048576 B fp32 scores[b*N+n][m]
#define WS_PART  2252800u    // 131072 B fp32 (max,sumexp) per (tile,wave) [4096][4][2]

// async global->LDS DMA, 16B/lane; offset must be an ICE -> fold into gp, pass 0
#define GLOAD_LDS(gp, lp) __builtin_amdgcn_global_load_lds( \
    (const __attribute__((address_space(1))) void*)(gp),    \
    (__attribute__((address_space(3))) void*)(lp), 16, 0, 0)

// ---------- prep: weight B-frags + projections (CwsF frag-swizzled) ----------
__global__ __launch_bounds__(256) void prep_kernel(
    const float* __restrict__ W1, const float* __restrict__ W2,
    const float* __restrict__ op_emb, const float* __restrict__ machine_emb,
    const float* __restrict__ b1, char* __restrict__ ws)
{
    if (blockIdx.x < 48) {               // weight fragment prep
        __bf16* WeB = (__bf16*)(ws + WS_WEB);
        __bf16* W2B = (__bf16*)(ws + WS_W2B);
        int idx = blockIdx.x * 256 + threadIdx.x;
        if (idx < 8192) {                // We: 16 frags (t 0..3, ks 0..3)
            int fid = idx >> 9, rem = idx & 511;
            int lane = rem >> 3, j = rem & 7;
            int t = fid >> 2, ks = fid & 3;
            int q = lane >> 4, ln = lane & 15;
            int d = ks * 32 + q * 8 + j;
            int h = t * 16 + ln;
            WeB[idx] = (__bf16)W1[(size_t)(2 * Dd + d) * Hh + h];
        } else {                         // W2: 8 frags (t 0..3, ks 0..1)
            int i2 = idx - 8192;
            int fid = i2 >> 9, rem = i2 & 511;
            int lane = rem >> 3, j = rem & 7;
            int t = fid >> 1, ks = fid & 1;
            int q = lane >> 4, ln = lane & 15;
            int k = ks * 32 + q * 8 + j;
            int h = t * 16 + ln;
            W2B[i2] = (__bf16)W2[(size_t)k * Hh + h];
        }
        return;
    }
    // projections: 1152 blocks x 4 rows (B*M + B*N = 4608 rows of 64)
    float* CwsF = (float*)(ws + WS_CWSF);
    float* Aop  = (float*)(ws + WS_AOP);
    const int bid = (blockIdx.x - 48) * 4 + (threadIdx.x >> 6);
    const int h = threadIdx.x & 63;
    if (bid < Bb * Mm) {
        const float* mg = machine_emb + (size_t)bid * Dd;
        const float* Wm = W1 + (size_t)Dd * Hh;
        float acc = b1[h];
#pragma unroll 8
        for (int d = 0; d < Dd; ++d) acc = fmaf(mg[d], Wm[d * Hh + h], acc);
        // scatter into fragment order: [b][w][t][lane=q*16+ln][r]
        int b = bid >> 6, m = bid & 63;
        int wq = m >> 4, q = (m >> 2) & 3, r = m & 3;
        int t = h >> 4, ln = h & 15;
        CwsF[((((b * 4 + wq) * 4 + t) * 64) + (q * 16 + ln)) * 4 + r] = acc;
    } else {
        const int bn = bid - Bb * Mm;
        const float* og = op_emb + (size_t)bn * Dd;
        float acc = 0.f;
#pragma unroll 8
        for (int d = 0; d < Dd; ++d) acc = fmaf(og[d], W1[d * Hh + h], acc);
        Aop[(size_t)bn * Hh + h] = acc;
    }
}

// ---------- main: block i, iter g -> tile bn = g*512 + i (b=g, n=i) ----------
// Memcpy-shaped read front: 512 resident blocks read 512 consecutive tiles.
__global__ __launch_bounds__(256, 2) void main_kernel(
    const float* __restrict__ edge_emb, const int* __restrict__ mask,
    const float* __restrict__ b2, const float* __restrict__ W3,
    const float* __restrict__ b3, char* __restrict__ ws)
{
    __shared__ float  sEdge[4 * 2 * BUFF];  // 66560 B: [wave][buf][seg][260 floats]
    __shared__ __bf16 sH1[Mm * 72];         //  9216 B  -> 75.8 KB, 2 blocks/CU

    float* scores = (float*)(ws + WS_SCORE);
    float* part   = (float*)(ws + WS_PART);
    const float* CwsF = (const float*)(ws + WS_CWSF);
    const float* Aop  = (const float*)(ws + WS_AOP);

    const int tid  = threadIdx.x;
    const int lane = tid & 63;
    const int w    = tid >> 6;
    const int q    = lane >> 4;
    const int ln   = lane & 15;
    const int i    = blockIdx.x;            // n = i, all batches
    const int wu   = __builtin_amdgcn_readfirstlane(w);

    // per-iteration tile base: tile bn = g*512+i; wave slab = w*8KB; lane 16B
    const float* e0 = edge_emb + (size_t)i * (Mm * Dd) + w * 2048 + lane * 4;
#define TILE_STRIDE ((size_t)512 * Mm * Dd)   // floats between consecutive g

    // ---- prologue DMAs: g=0 -> buf0, g=1 -> buf1 ----
    {
        float* d0 = &sEdge[(wu * 2 + 0) * BUFF];
        float* d1 = &sEdge[(wu * 2 + 1) * BUFF];
#pragma unroll
        for (int s = 0; s < 8; ++s) GLOAD_LDS(e0 + s * 256, d0 + s * SEGF);
#pragma unroll
        for (int s = 0; s < 8; ++s) GLOAD_LDS(e0 + TILE_STRIDE + s * 256, d1 + s * SEGF);
    }

    // ---- loop-invariant: weights into registers ----
    bf16x8 weF[16], w2F[8];
    {
        const bf16x8* WeB = (const bf16x8*)(ws + WS_WEB);
        const bf16x8* W2B = (const bf16x8*)(ws + WS_W2B);
#pragma unroll
        for (int f = 0; f < 16; ++f) weF[f] = WeB[f * 64 + lane];
#pragma unroll
        for (int f = 0; f < 8; ++f)  w2F[f] = W2B[f * 64 + lane];
    }
    float b2v[4], w3v[4];
#pragma unroll
    for (int t = 0; t < 4; ++t) { b2v[t] = b2[t * 16 + ln]; w3v[t] = W3[t * 16 + ln]; }
    const float bias3 = b3[0];

    // A-frag LDS read offset: row ln -> seg ln>>1, half ln&1; +q*8
    const int rdoff = (ln >> 1) * SEGF + (ln & 1) * 128 + q * 8;

#pragma unroll
    for (int g = 0; g < Bb; ++g) {          // batch b = g, tile bn = g*512+i
        const int bn = g * 512 + i;
        const int buf = g & 1;
        const float* ldsrd = &sEdge[(wu * 2 + buf) * BUFF];

        // ensure tile g's DMA batch landed: keep (refill 8 + 2 stores) newest
        __builtin_amdgcn_s_waitcnt(0x0F7A);   // vmcnt(10)

        f32x4 lo[4], hi[4];
#pragma unroll
        for (int ks = 0; ks < 4; ++ks) {
            lo[ks] = *(const f32x4*)&ldsrd[rdoff + ks * 32];
            hi[ks] = *(const f32x4*)&ldsrd[rdoff + ks * 32 + 4];
        }
        bf16x8 af[4];
#pragma unroll
        for (int ks = 0; ks < 4; ++ks) {
            bf16x8 a;
            a[0] = (__bf16)lo[ks][0]; a[1] = (__bf16)lo[ks][1];
            a[2] = (__bf16)lo[ks][2]; a[3] = (__bf16)lo[ks][3];
            a[4] = (__bf16)hi[ks][0]; a[5] = (__bf16)hi[ks][1];
            a[6] = (__bf16)hi[ks][2]; a[7] = (__bf16)hi[ks][3];
            af[ks] = a;
        }

        // per-iteration small loads (L2-hot); issued BEFORE refill so the
        // compiler's auto-wait for their uses is vmcnt(8) (keeps refill pending)
        f32x4 cv[4];
#pragma unroll
        for (int t = 0; t < 4; ++t)
            cv[t] = *(const f32x4*)&CwsF[((((g * 4 + w) * 4 + t) * 64) + lane) * 4];
        float aopv[4];
#pragma unroll
        for (int t = 0; t < 4; ++t) aopv[t] = Aop[(size_t)bn * Hh + t * 16 + ln];
        const int4 mk = *(const int4*)&mask[(size_t)bn * Mm + w * 16 + q * 4];

        // refill this buffer with tile g+2
        if (g + 2 < Bb) {
            float* dst = &sEdge[(wu * 2 + buf) * BUFF];
            const float* src = e0 + (size_t)(g + 2) * TILE_STRIDE;
#pragma unroll
            for (int s = 0; s < 8; ++s) GLOAD_LDS(src + s * 256, dst + s * SEGF);
        }

        // GEMM1: D = edge . We  (projections added in epilogue, before relu)
        f32x4 acc[4];
#pragma unroll
        for (int t = 0; t < 4; ++t) acc[t] = (f32x4){0.f, 0.f, 0.f, 0.f};
#pragma unroll
        for (int t = 0; t < 4; ++t)
#pragma unroll
            for (int ks = 0; ks < 4; ++ks)
                acc[t] = __builtin_amdgcn_mfma_f32_16x16x32_bf16(af[ks], weF[t * 4 + ks], acc[t], 0, 0, 0);

        // epilogue 1: relu(D + Aop + Cws) -> sH1 (wave-private rows, no barrier)
#pragma unroll
        for (int t = 0; t < 4; ++t)
#pragma unroll
            for (int r = 0; r < 4; ++r)
                sH1[(w * 16 + q * 4 + r) * 72 + t * 16 + ln] =
                    (__bf16)fmaxf(acc[t][r] + aopv[t] + cv[t][r], 0.f);

        // GEMM2
        bf16x8 a2[2];
#pragma unroll
        for (int ks = 0; ks < 2; ++ks)
            a2[ks] = *(const bf16x8*)&sH1[(w * 16 + ln) * 72 + ks * 32 + q * 8];
        f32x4 c2[4];
#pragma unroll
        for (int t = 0; t < 4; ++t) c2[t] = (f32x4){0.f, 0.f, 0.f, 0.f};
#pragma unroll
        for (int t = 0; t < 4; ++t)
#pragma unroll
            for (int ks = 0; ks < 2; ++ks)
                c2[t] = __builtin_amdgcn_mfma_f32_16x16x32_bf16(a2[ks], w2F[t * 2 + ks], c2[t], 0, 0, 0);

        // epilogue 2: masked scores + per-wave softmax partial for batch g
        float p[4] = {0.f, 0.f, 0.f, 0.f};
#pragma unroll
        for (int t = 0; t < 4; ++t)
#pragma unroll
            for (int r = 0; r < 4; ++r)
                p[r] += fmaxf(c2[t][r] + b2v[t], 0.f) * w3v[t];
#pragma unroll
        for (int r = 0; r < 4; ++r) {
            p[r] += __shfl_xor(p[r], 1, 64);
            p[r] += __shfl_xor(p[r], 2, 64);
            p[r] += __shfl_xor(p[r], 4, 64);
            p[r] += __shfl_xor(p[r], 8, 64);
        }
        const int m0 = w * 16 + q * 4;
        const int mkv[4] = {mk.x, mk.y, mk.z, mk.w};
        float m_loc = NEG_BIG, l_loc = 0.f;
        float vv[4];
#pragma unroll
        for (int r = 0; r < 4; ++r) {
            float v = p[r] + bias3;
            vv[r] = mkv[r] ? v : NEG_BIG;
            if (mkv[r]) {
                float mn = fmaxf(m_loc, v);
                l_loc = l_loc * expf(m_loc - mn) + expf(v - mn);
                m_loc = mn;
            }
        }
        if (ln == 0) {
            float4 o; o.x = vv[0]; o.y = vv[1]; o.z = vv[2]; o.w = vv[3];
            *(float4*)&scores[(size_t)bn * Mm + m0] = o;
        }
        // combine q-groups within the wave (rows m0..m15 of tile bn)
#pragma unroll
        for (int off = 16; off <= 32; off <<= 1) {
            float mo = __shfl_xor(m_loc, off, 64);
            float lo2 = __shfl_xor(l_loc, off, 64);
            float mn = fmaxf(m_loc, mo);
            l_loc = l_loc * expf(m_loc - mn) + lo2 * expf(mo - mn);
            m_loc = mn;
        }
        if (lane == 0) {
            float2 o; o.x = m_loc; o.y = l_loc;
            *(float2*)&part[((size_t)bn * 4 + w) * 2] = o;
        }
    }
}

// ---------- log-softmax: combine 2048 per-wave partials per batch, apply ----------
__global__ __launch_bounds__(256) void lsm_apply_kernel(
    const char* __restrict__ ws, float* __restrict__ out)
{
    const float4* s4 = (const float4*)(ws + WS_SCORE);
    const float* part = (const float*)(ws + WS_PART);
    __shared__ float sComb[8];
    __shared__ float sCC;
    const int tid = threadIdx.x;
    const int b = blockIdx.x >> 5;       // 32 blocks per batch; 2048 partials each
    {
        float m_loc = NEG_BIG, l_loc = 0.f;
        const float* pb = &part[(size_t)b * 4096];   // 2048 float2, contiguous
#pragma unroll
        for (int k = 0; k < 8; ++k) {
            float2 p = *(const float2*)&pb[(tid * 8 + k) * 2];
            float mn = fmaxf(m_loc, p.x);
            l_loc = l_loc * expf(m_loc - mn) + p.y * expf(p.x - mn);
            m_loc = mn;
        }
#pragma unroll
        for (int off = 1; off < 64; off <<= 1) {
            float mo = __shfl_xor(m_loc, off, 64);
            float lo2 = __shfl_xor(l_loc, off, 64);
            float nm = fmaxf(m_loc, mo);
            l_loc = l_loc * expf(m_loc - nm) + lo2 * expf(mo - nm);
            m_loc = nm;
        }
        if ((tid & 63) == 0) { sComb[(tid >> 6) * 2] = m_loc; sComb[(tid >> 6) * 2 + 1] = l_loc; }
    }
    __syncthreads();
    if (tid == 0) {
        float gm = sComb[0], gl = sComb[1];
#pragma unroll
        for (int k = 1; k < 4; ++k) {
            float mo = sComb[k * 2], lo2 = sComb[k * 2 + 1];
            float mn = fmaxf(gm, mo);
            gl = gl * expf(gm - mn) + lo2 * expf(mo - mn);
            gm = mn;
        }
        sCC = gm + logf(gl);
    }
    __syncthreads();
    const float c = sCC;
    const int idx = blockIdx.x * 256 + tid;    // 65536 float4s
    float4 v = s4[idx];
    v.x -= c; v.y -= c; v.z -= c; v.w -= c;
    ((float4*)out)[idx] = v;
}

extern "C" void kernel_launch(void* const* d_in, const int* in_sizes, int n_in,
                              void* d_out, int out_size, void* d_ws, size_t ws_size,
                              hipStream_t stream)
{
    const float* op_emb      = (const float*)d_in[0];
    const float* machine_emb = (const float*)d_in[1];
    const float* edge_emb    = (const float*)d_in[2];
    const int*   mask        = (const int*)  d_in[3];
    const float* W1 = (const float*)d_in[4];
    const float* b1 = (const float*)d_in[5];
    const float* W2 = (const float*)d_in[6];
    const float* b2 = (const float*)d_in[7];
    const float* W3 = (const float*)d_in[8];
    const float* b3 = (const float*)d_in[9];
    char* ws = (char*)d_ws;

    prep_kernel<<<48 + 1152, 256, 0, stream>>>(W1, W2, op_emb, machine_emb, b1, ws);
    main_kernel<<<Nn, 256, 0, stream>>>(edge_emb, mask, b2, W3, b3, ws);
    lsm_apply_kernel<<<256, 256, 0, stream>>>(ws, (float*)d_out);
}

// Round 13
// 228.815 us; speedup vs baseline: 1.0037x; 1.0037x over previous
//
#include <hip/hip_runtime.h>
#include <math.h>

#define Bb 8
#define Nn 512
#define Mm 64
#define Dd 128
#define Hh 64
#define Gg 8                 // n's per block; grid = 4096/8 = 512 = 2 blocks/CU
#define NEG_BIG (-1.0e30f)

// per-wave edge buffer: 8 segments of 1KB, each padded +16B -> 260 floats
#define SEGF 260
#define BUFF (8 * SEGF)      // 2080 floats per buffer

typedef __bf16 bf16x8 __attribute__((ext_vector_type(8)));
typedef float  f32x4  __attribute__((ext_vector_type(4)));

// ws byte offsets (16B-aligned)
#define WS_WEB   0u          // 16384 B  bf16 We B-frags, frag-linear [16 frag][64 lane][8]
#define WS_WMB   16384u      // 16384 B  bf16 Wm B-frags, frag-linear
#define WS_W2B   32768u      // 8192 B   bf16 W2 B-frags, frag-linear
#define WS_SCORE 49152u      // 1048576 B fp32 scores[b*N+n][m]
#define WS_PART  1097728u    // 4096 B   fp32 (max,sumexp) per block [512][2]

// async global->LDS DMA, 16B/lane; offset must be an ICE -> fold into gp, pass 0
#define GLOAD_LDS(gp, lp) __builtin_amdgcn_global_load_lds( \
    (const __attribute__((address_space(1))) void*)(gp),    \
    (__attribute__((address_space(3))) void*)(lp), 16, 0, 0)

// ---------- prep: weight B-frags only (We, Wm, W2) ----------
__global__ __launch_bounds__(256) void prep_kernel(
    const float* __restrict__ W1, const float* __restrict__ W2, char* __restrict__ ws)
{
    int idx = blockIdx.x * 256 + threadIdx.x;        // 80 blocks -> 20480 elems
    if (idx < 16384) {                               // We (rows 2D:3D) / Wm (rows D:2D)
        int e = idx & 8191;
        int fid = e >> 9, rem = e & 511;
        int lane = rem >> 3, j = rem & 7;
        int t = fid >> 2, ks = fid & 3;
        int q = lane >> 4, ln = lane & 15;
        int d = ks * 32 + q * 8 + j;
        int h = t * 16 + ln;
        if (idx < 8192)
            ((__bf16*)(ws + WS_WEB))[e] = (__bf16)W1[(size_t)(2 * Dd + d) * Hh + h];
        else
            ((__bf16*)(ws + WS_WMB))[e] = (__bf16)W1[(size_t)(Dd + d) * Hh + h];
    } else if (idx < 20480) {                        // W2: 8 frags (t 0..3, ks 0..1)
        int e = idx - 16384;
        int fid = e >> 9, rem = e & 511;
        int lane = rem >> 3, j = rem & 7;
        int t = fid >> 1, ks = fid & 1;
        int q = lane >> 4, ln = lane & 15;
        int k = ks * 32 + q * 8 + j;
        int h = t * 16 + ln;
        ((__bf16*)(ws + WS_W2B))[e] = (__bf16)W2[(size_t)k * Hh + h];
    }
}

// ---------- main: R9 structure + machine pre-iteration + inline Aop ----------
__global__ __launch_bounds__(256, 2) void main_kernel(
    const float* __restrict__ edge_emb, const float* __restrict__ machine_emb,
    const float* __restrict__ op_emb, const float* __restrict__ W1,
    const float* __restrict__ b1, const int* __restrict__ mask,
    const float* __restrict__ b2, const float* __restrict__ W3,
    const float* __restrict__ b3, char* __restrict__ ws)
{
    __shared__ float  sEdge[4 * 2 * BUFF];  // 66560 B: [wave][buf][seg][260 floats]
    __shared__ float  sAop[Gg * Hh];        //  2048 B
    __shared__ int    sMask[Gg * Mm];       //  2048 B
    __shared__ __bf16 sH1[Mm * 72];         //  9216 B
    __shared__ float  sRed[8];              //    32 B  -> ~79 KB, 2 blocks/CU

    float* scores = (float*)(ws + WS_SCORE);
    float* part   = (float*)(ws + WS_PART);

    const int tid  = threadIdx.x;
    const int lane = tid & 63;
    const int w    = tid >> 6;
    const int q    = lane >> 4;
    const int ln   = lane & 15;
    const int bn0  = blockIdx.x * Gg;
    const int b    = bn0 >> 9;              // 64 blocks per batch; never straddles
    const int wu   = __builtin_amdgcn_readfirstlane(w);

    // ---- weight fragments into registers (issued before DMAs) ----
    bf16x8 weF[16], w2F[8], wmF[16];
    {
        const bf16x8* WeB = (const bf16x8*)(ws + WS_WEB);
        const bf16x8* WmB = (const bf16x8*)(ws + WS_WMB);
        const bf16x8* W2B = (const bf16x8*)(ws + WS_W2B);
#pragma unroll
        for (int f = 0; f < 16; ++f) weF[f] = WeB[f * 64 + lane];
#pragma unroll
        for (int f = 0; f < 16; ++f) wmF[f] = WmB[f * 64 + lane];
#pragma unroll
        for (int f = 0; f < 8; ++f)  w2F[f] = W2B[f * 64 + lane];
    }

    // wave w's slab base (rows w*16..w*16+15), lane 16B
    const float* ebase = edge_emb + (size_t)bn0 * (Mm * Dd) + w * 2048 + lane * 4;
    const float* mbase = machine_emb + (size_t)b * (Mm * Dd) + w * 2048 + lane * 4;

    // ---- prologue DMAs: machine -> buf0, edge tile0 -> buf1 ----
    {
        float* d0 = &sEdge[(wu * 2 + 0) * BUFF];
        float* d1 = &sEdge[(wu * 2 + 1) * BUFF];
#pragma unroll
        for (int s = 0; s < 8; ++s) GLOAD_LDS(mbase + s * 256, d0 + s * SEGF);
#pragma unroll
        for (int s = 0; s < 8; ++s) GLOAD_LDS(ebase + s * 256, d1 + s * SEGF);
    }

    // ---- cooperative Aop: 512 values (8 n x 64 h), 2 per thread ----
    {
        const int an = tid >> 5;                 // n index 0..7
        const int ah = (tid * 2) & 63;           // h, h+1
        const float* orow = op_emb + (size_t)(bn0 + an) * Dd;
        float a0 = 0.f, a1 = 0.f;
#pragma unroll 8
        for (int d = 0; d < Dd; ++d) {
            float o = orow[d];
            a0 = fmaf(o, W1[d * Hh + ah], a0);
            a1 = fmaf(o, W1[d * Hh + ah + 1], a1);
        }
        sAop[an * 64 + ah] = a0;
        sAop[an * 64 + ah + 1] = a1;
    }
    if (tid < 128)
        ((int4*)sMask)[tid] = ((const int4*)mask)[(size_t)bn0 * 16 + tid];

    float b2v[4], w3v[4], b1v[4];
#pragma unroll
    for (int t = 0; t < 4; ++t) {
        b2v[t] = b2[t * 16 + ln]; w3v[t] = W3[t * 16 + ln]; b1v[t] = b1[t * 16 + ln];
    }
    const float bias3 = b3[0];

    // A-frag LDS read offset: row ln -> seg ln>>1, half ln&1; +q*8
    const int rdoff = (ln >> 1) * SEGF + (ln & 1) * 128 + q * 8;

    // ---- machine pre-iteration: cv[t] = machine . Wm + b1 (C/D layout regs) ----
    f32x4 cv[4];
    {
        __builtin_amdgcn_s_waitcnt(0x0F78);   // vmcnt(8): drain machine, keep tile0
        const float* ldsrd = &sEdge[(wu * 2 + 0) * BUFF];
        f32x4 lo[4], hi[4];
#pragma unroll
        for (int ks = 0; ks < 4; ++ks) {
            lo[ks] = *(const f32x4*)&ldsrd[rdoff + ks * 32];
            hi[ks] = *(const f32x4*)&ldsrd[rdoff + ks * 32 + 4];
        }
        bf16x8 am[4];
#pragma unroll
        for (int ks = 0; ks < 4; ++ks) {
            bf16x8 a;
            a[0] = (__bf16)lo[ks][0]; a[1] = (__bf16)lo[ks][1];
            a[2] = (__bf16)lo[ks][2]; a[3] = (__bf16)lo[ks][3];
            a[4] = (__bf16)hi[ks][0]; a[5] = (__bf16)hi[ks][1];
            a[6] = (__bf16)hi[ks][2]; a[7] = (__bf16)hi[ks][3];
            am[ks] = a;
        }
        // refill buf0 with edge tile1 (machine reads consumed above)
        {
            float* dst = &sEdge[(wu * 2 + 0) * BUFF];
            const float* src = ebase + 8192;
#pragma unroll
            for (int s = 0; s < 8; ++s) GLOAD_LDS(src + s * 256, dst + s * SEGF);
        }
#pragma unroll
        for (int t = 0; t < 4; ++t)
            cv[t] = (f32x4){b1v[t], b1v[t], b1v[t], b1v[t]};
#pragma unroll
        for (int t = 0; t < 4; ++t)
#pragma unroll
            for (int ks = 0; ks < 4; ++ks)
                cv[t] = __builtin_amdgcn_mfma_f32_16x16x32_bf16(am[ks], wmF[t * 4 + ks], cv[t], 0, 0, 0);
    }

    float m_loc = NEG_BIG, l_loc = 0.f;     // per-lane online softmax state

    __syncthreads();   // sAop/sMask visible (drains outstanding DMAs too; once)

#pragma unroll
    for (int g = 0; g < Gg; ++g) {
        // tile g lives in buf (g+1)&1  (t0 -> buf1, t1 -> buf0, ...)
        const int buf = (g + 1) & 1;
        const float* ldsrd = &sEdge[(wu * 2 + buf) * BUFF];

        // drain the tile being consumed; keep the in-flight refill pending
        if (g == Gg - 1) __builtin_amdgcn_s_waitcnt(0x0F70);  // vmcnt(0) at tail
        else             __builtin_amdgcn_s_waitcnt(0x0F78);  // vmcnt(8)

        f32x4 lo[4], hi[4];
#pragma unroll
        for (int ks = 0; ks < 4; ++ks) {
            lo[ks] = *(const f32x4*)&ldsrd[rdoff + ks * 32];
            hi[ks] = *(const f32x4*)&ldsrd[rdoff + ks * 32 + 4];
        }
        bf16x8 af[4];
#pragma unroll
        for (int ks = 0; ks < 4; ++ks) {
            bf16x8 a;
            a[0] = (__bf16)lo[ks][0]; a[1] = (__bf16)lo[ks][1];
            a[2] = (__bf16)lo[ks][2]; a[3] = (__bf16)lo[ks][3];
            a[4] = (__bf16)hi[ks][0]; a[5] = (__bf16)hi[ks][1];
            a[6] = (__bf16)hi[ks][2]; a[7] = (__bf16)hi[ks][3];
            af[ks] = a;
        }

        // refill this buffer with tile g+2 (reads consumed above)
        if (g + 2 < Gg) {
            float* dst = &sEdge[(wu * 2 + buf) * BUFF];
            const float* src = ebase + (size_t)(g + 2) * 8192;
#pragma unroll
            for (int s = 0; s < 8; ++s) GLOAD_LDS(src + s * 256, dst + s * SEGF);
        }

        // GEMM1: D = edge . We   (A+C added in epilogue before relu)
        f32x4 acc[4];
#pragma unroll
        for (int t = 0; t < 4; ++t) acc[t] = (f32x4){0.f, 0.f, 0.f, 0.f};
#pragma unroll
        for (int t = 0; t < 4; ++t)
#pragma unroll
            for (int ks = 0; ks < 4; ++ks)
                acc[t] = __builtin_amdgcn_mfma_f32_16x16x32_bf16(af[ks], weF[t * 4 + ks], acc[t], 0, 0, 0);

        // epilogue 1: relu(D + Aop + Cws) -> sH1 (wave-private rows, no barrier)
#pragma unroll
        for (int t = 0; t < 4; ++t) {
            float av = sAop[g * Hh + t * 16 + ln];
#pragma unroll
            for (int r = 0; r < 4; ++r)
                sH1[(w * 16 + q * 4 + r) * 72 + t * 16 + ln] =
                    (__bf16)fmaxf(acc[t][r] + av + cv[t][r], 0.f);
        }

        // GEMM2
        bf16x8 a2[2];
#pragma unroll
        for (int ks = 0; ks < 2; ++ks)
            a2[ks] = *(const bf16x8*)&sH1[(w * 16 + ln) * 72 + ks * 32 + q * 8];
        f32x4 c2[4];
#pragma unroll
        for (int t = 0; t < 4; ++t) c2[t] = (f32x4){0.f, 0.f, 0.f, 0.f};
#pragma unroll
        for (int t = 0; t < 4; ++t)
#pragma unroll
            for (int ks = 0; ks < 2; ++ks)
                c2[t] = __builtin_amdgcn_mfma_f32_16x16x32_bf16(a2[ks], w2F[t * 2 + ks], c2[t], 0, 0, 0);

        // epilogue 2: masked scores + online softmax partials
        float p[4] = {0.f, 0.f, 0.f, 0.f};
#pragma unroll
        for (int t = 0; t < 4; ++t)
#pragma unroll
            for (int r = 0; r < 4; ++r)
                p[r] += fmaxf(c2[t][r] + b2v[t], 0.f) * w3v[t];
#pragma unroll
        for (int r = 0; r < 4; ++r) {
            p[r] += __shfl_xor(p[r], 1, 64);
            p[r] += __shfl_xor(p[r], 2, 64);
            p[r] += __shfl_xor(p[r], 4, 64);
            p[r] += __shfl_xor(p[r], 8, 64);
        }
        const int m0 = w * 16 + q * 4;
        const int* mrow = &sMask[g * Mm + m0];
        float vv[4];
#pragma unroll
        for (int r = 0; r < 4; ++r) {
            float v = p[r] + bias3;
            vv[r] = mrow[r] ? v : NEG_BIG;
            if (mrow[r]) {
                float mn = fmaxf(m_loc, v);
                l_loc = l_loc * expf(m_loc - mn) + expf(v - mn);
                m_loc = mn;
            }
        }
        if (ln == 0) {
            float4 o; o.x = vv[0]; o.y = vv[1]; o.z = vv[2]; o.w = vv[3];
            *(float4*)&scores[(size_t)(bn0 + g) * Mm + m0] = o;
        }
    }

    // ---- block softmax partial: combine q-groups (xor 16,32), then waves ----
#pragma unroll
    for (int off = 16; off <= 32; off <<= 1) {
        float mo = __shfl_xor(m_loc, off, 64);
        float lo2 = __shfl_xor(l_loc, off, 64);
        float mn = fmaxf(m_loc, mo);
        l_loc = l_loc * expf(m_loc - mn) + lo2 * expf(mo - mn);
        m_loc = mn;
    }
    if (lane == 0) { sRed[w * 2] = m_loc; sRed[w * 2 + 1] = l_loc; }
    __syncthreads();
    if (tid == 0) {
        float gm = sRed[0], gl = sRed[1];
#pragma unroll
        for (int k = 1; k < 4; ++k) {
            float mo = sRed[k * 2], lo2 = sRed[k * 2 + 1];
            float mn = fmaxf(gm, mo);
            gl = gl * expf(gm - mn) + lo2 * expf(mo - mn);
            gm = mn;
        }
        float2 o; o.x = gm; o.y = gl;
        *(float2*)&part[blockIdx.x * 2] = o;
    }
}

// ---------- log-softmax: combine 64 partials per batch inline, apply ----------
__global__ __launch_bounds__(256) void lsm_apply_kernel(
    const char* __restrict__ ws, float* __restrict__ out)
{
    const float4* s4 = (const float4*)(ws + WS_SCORE);
    const float* part = (const float*)(ws + WS_PART);
    __shared__ float sCC;
    const int tid = threadIdx.x;
    const int b = blockIdx.x >> 5;       // 32 blocks per batch
    if (tid < 64) {                      // inline combine of 64 partials
        float2 p = *(const float2*)&part[(b * 64 + tid) * 2];
        float gm = p.x;
#pragma unroll
        for (int off = 1; off < 64; off <<= 1) gm = fmaxf(gm, __shfl_xor(gm, off, 64));
        float l = p.y * expf(p.x - gm);
#pragma unroll
        for (int off = 1; off < 64; off <<= 1) l += __shfl_xor(l, off, 64);
        if (tid == 0) sCC = gm + logf(l);
    }
    __syncthreads();
    const float c = sCC;
    const int i = blockIdx.x * 256 + tid;    // 65536 float4s
    float4 v = s4[i];
    v.x -= c; v.y -= c; v.z -= c; v.w -= c;
    ((float4*)out)[i] = v;
}

extern "C" void kernel_launch(void* const* d_in, const int* in_sizes, int n_in,
                              void* d_out, int out_size, void* d_ws, size_t ws_size,
                              hipStream_t stream)
{
    const float* op_emb      = (const float*)d_in[0];
    const float* machine_emb = (const float*)d_in[1];
    const float* edge_emb    = (const float*)d_in[2];
    const int*   mask        = (const int*)  d_in[3];
    const float* W1 = (const float*)d_in[4];
    const float* b1 = (const float*)d_in[5];
    const float* W2 = (const float*)d_in[6];
    const float* b2 = (const float*)d_in[7];
    const float* W3 = (const float*)d_in[8];
    const float* b3 = (const float*)d_in[9];
    char* ws = (char*)d_ws;

    prep_kernel<<<80, 256, 0, stream>>>(W1, W2, ws);
    main_kernel<<<(Bb * Nn) / Gg, 256, 0, stream>>>(edge_emb, machine_emb, op_emb,
                                                    W1, b1, mask, b2, W3, b3, ws);
    lsm_apply_kernel<<<256, 256, 0, stream>>>(ws, (float*)d_out);
}